// Round 7
// baseline (264.741 us; speedup 1.0000x reference)
//
#include <hip/hip_runtime.h>
#include <hip/hip_bf16.h>
#include <math.h>
#include <float.h>

// Problem constants (x: [8192,128] f32, n_images=2)
static constexpr int NN    = 8192;
static constexpr int DD    = 128;
static constexpr int PP    = 4096;              // persons
static constexpr int TILE  = 128;
static constexpr int TT    = NN / TILE;         // 64 tiles per dim
static constexpr int NBLK  = TT * (TT + 1) / 2; // 2080 upper-tri tile pairs
static constexpr int NC    = NBLK * 2;          // 2 candidates per tile
static constexpr int GRP   = 1088;              // 8 rows x 128B (fp8) + 64B pad
static constexpr int PLDS  = 16 * GRP;          // 17408 B per 128x128 fp8 panel

struct Cand { float v; unsigned idx; };

using f32x4 = __attribute__((ext_vector_type(4))) float;

typedef const __attribute__((address_space(1))) unsigned int* gas_uint;
typedef __attribute__((address_space(3))) unsigned int* las_uint;

// async 16B/lane global->LDS DMA. LDS dest = wave-uniform base + lane*16.
// Global address may vary per lane. [m03/m97/m104]
__device__ __forceinline__ void dma16(const void* g, const void* l) {
    __builtin_amdgcn_global_load_lds(
        (gas_uint)(unsigned long long)g,
        (las_uint)(unsigned)(unsigned long long)l, 16, 0, 0);
}

__device__ __forceinline__ void push1(float& v1, unsigned& i1, float& v2, unsigned& i2,
                                      float w, unsigned j) {
    if (w > v1) { v2 = v1; i2 = i1; v1 = w; i1 = j; }
    else if (w > v2) { v2 = w; i2 = j; }
}

__device__ __forceinline__ void merge2(float& v1, unsigned& i1, float& v2, unsigned& i2,
                                       float w1, unsigned j1, float w2, unsigned j2) {
    if (w1 > v1) {
        float nv2; unsigned ni2;
        if (v1 >= w2) { nv2 = v1; ni2 = i1; } else { nv2 = w2; ni2 = j2; }
        v1 = w1; i1 = j1; v2 = nv2; i2 = ni2;
    } else if (w1 > v2) {
        v2 = w1; i2 = j1;
    }
}

__device__ __forceinline__ void dmerge2(double& v1, unsigned& i1, double& v2,
                                        double w1, unsigned j1, double w2) {
    if (w1 > v1) {
        double nv2 = (v1 >= w2) ? v1 : w2;
        v2 = nv2; v1 = w1; i1 = j1;
    } else if (w1 > v2) {
        v2 = w1;
    }
}

// ---- kernel 0: x -> fp8 e4m3 (1MB) + sim_self (double) + done-ctr reset.
// 128 blocks only (launch-ramp diet): each converts 512 grid-strided chunks
// and computes 32 persons' sim_self. ----
__global__ __launch_bounds__(256) void k_prep(const float* __restrict__ x,
                                              unsigned char* __restrict__ xb,
                                              double* __restrict__ ss,
                                              int* __restrict__ ctrl) {
    const int tid = threadIdx.x;
    const int bid = blockIdx.x;
    if (bid == 0 && tid == 0) ctrl[0] = 0;     // done counter (graph-replay reset)

    // convert: 65536 chunks x 16 floats -> 16 fp8; 2 chunks per thread
    for (int chunk = bid * 256 + tid; chunk < 65536; chunk += 128 * 256) {
        const float4* s = (const float4*)(x + (size_t)chunk * 16);
        float4 f0 = s[0], f1 = s[1], f2 = s[2], f3 = s[3];
        unsigned w0 = 0, w1 = 0, w2 = 0, w3 = 0;
        w0 = __builtin_amdgcn_cvt_pk_fp8_f32(f0.x, f0.y, w0, false);
        w0 = __builtin_amdgcn_cvt_pk_fp8_f32(f0.z, f0.w, w0, true);
        w1 = __builtin_amdgcn_cvt_pk_fp8_f32(f1.x, f1.y, w1, false);
        w1 = __builtin_amdgcn_cvt_pk_fp8_f32(f1.z, f1.w, w1, true);
        w2 = __builtin_amdgcn_cvt_pk_fp8_f32(f2.x, f2.y, w2, false);
        w2 = __builtin_amdgcn_cvt_pk_fp8_f32(f2.z, f2.w, w2, true);
        w3 = __builtin_amdgcn_cvt_pk_fp8_f32(f3.x, f3.y, w3, false);
        w3 = __builtin_amdgcn_cvt_pk_fp8_f32(f3.z, f3.w, w3, true);
        uint4 o = {w0, w1, w2, w3};
        *(uint4*)(xb + (size_t)chunk * 16) = o;
    }

    // sim_self[p] = dot(x[p], x[p+1]) in double, wave per person, 8 each
    const int wv = tid >> 6, lane = tid & 63;
    #pragma unroll
    for (int u = 0; u < 8; ++u) {
        int p = bid * 32 + wv * 8 + u;         // 0..4095
        const float* a  = x + (size_t)p * DD;
        const float* bb = a + DD;
        double s = (double)a[lane] * (double)bb[lane]
                 + (double)a[lane + 64] * (double)bb[lane + 64];
        #pragma unroll
        for (int off = 32; off >= 1; off >>= 1) s += __shfl_down(s, off);
        if (lane == 0) ss[p] = s;
    }
}

// ---- kernel 1 (fused): verbatim R3 fp8 MFMA top-2 body (97us measured) +
// last-block-done finalize (approx top-2 -> exact f64 recheck -> mean).
// One kernel boundary and the 1-WG k_final launch eliminated. ----
__global__ __launch_bounds__(256, 4) void k_fused(const unsigned char* __restrict__ xb,
                                                  const float* __restrict__ x,
                                                  const double* __restrict__ ss,
                                                  Cand* __restrict__ cands,
                                                  int* __restrict__ ctrl,
                                                  float* __restrict__ out) {
    __shared__ __align__(16) char As[PLDS];
    __shared__ __align__(16) char Bs[PLDS];
    __shared__ float sv1[4], sv2[4];
    __shared__ unsigned si1[4], si2[4];
    __shared__ int s_last;

    const int tid  = threadIdx.x;
    const int wv   = tid >> 6;      // wave 0..3
    const int lane = tid & 63;

    // decode linear block id -> (ti, tj), ti <= tj
    int rem = blockIdx.x;
    int ti = 0;
    while (rem >= TT - ti) { rem -= (TT - ti); ++ti; }
    const int tj = ti + rem;

    // ---- stage both 128x128 fp8 panels, single phase, 8 dma16 per wave.
    // group = 8 rows x 128B. Source col XOR-swizzled by (row_in<<4) so the
    // linear LDS write gives conflict-free fragment reads.
    {
        const int grow = lane >> 3;                 // 0..7
        const int colb = ((lane & 7) * 16) ^ (grow << 4);
        #pragma unroll
        for (int t = 0; t < 4; ++t) {
            int g = wv * 4 + t;                     // group 0..15
            dma16(xb + (size_t)(ti * TILE + g * 8 + grow) * DD + colb, As + g * GRP);
            dma16(xb + (size_t)(tj * TILE + g * 8 + grow) * DD + colb, Bs + g * GRP);
        }
    }
    __syncthreads();   // vmcnt(0) drain before s_barrier -> DMA landed

    const int wm   = wv >> 1;       // wave row 0..1 (64 rows)
    const int wn   = wv & 1;        // wave col 0..1 (64 cols)
    const int quad = lane >> 4;     // 0..3
    const int r16  = lane & 15;     // 0..15
    const int rl   = r16 & 7;       // row within group
    const int rh   = r16 >> 3;      // group parity within 16-row fragment
    const int xs   = rl << 4;       // XOR term matching the staging swizzle

    const char* Abase = As + (wm * 8 + rh) * GRP + rl * 128 + (quad & 1) * 8;
    const char* Bbase = Bs + (wn * 8 + rh) * GRP + rl * 128 + (quad & 1) * 8;

    f32x4 acc[4][4];
    #pragma unroll
    for (int mi = 0; mi < 4; ++mi)
        #pragma unroll
        for (int nj = 0; nj < 4; ++nj)
            acc[mi][nj] = (f32x4){0.f, 0.f, 0.f, 0.f};

    #pragma unroll
    for (int kc = 0; kc < 4; ++kc) {        // 4 chunks of K=32
        const int co = (kc * 32 + (quad >> 1) * 16) ^ xs;
        long af[4], bq[4];
        #pragma unroll
        for (int mi = 0; mi < 4; ++mi) {
            af[mi] = *(const long*)(Abase + mi * (2 * GRP) + co);
            bq[mi] = *(const long*)(Bbase + mi * (2 * GRP) + co);
        }
        #pragma unroll
        for (int mi = 0; mi < 4; ++mi)
            #pragma unroll
            for (int nj = 0; nj < 4; ++nj)
                acc[mi][nj] = __builtin_amdgcn_mfma_f32_16x16x32_fp8_fp8(
                    af[mi], bq[nj], acc[mi][nj], 0, 0, 0);
    }

    // ---- epilogue: per-lane top-2 over valid (i<j) ----
    // C/D layout: col = lane&15, row = (lane>>4)*4 + reg (dtype-independent)
    const int ibase = ti * TILE + wm * 64;
    const int jbase = tj * TILE + wn * 64;
    float v1 = -INFINITY, v2 = -INFINITY;
    unsigned i1 = 0, i2 = 0;
    #pragma unroll
    for (int mi = 0; mi < 4; ++mi) {
        #pragma unroll
        for (int nj = 0; nj < 4; ++nj) {
            int gj = jbase + nj * 16 + r16;
            #pragma unroll
            for (int reg = 0; reg < 4; ++reg) {
                int gi = ibase + mi * 16 + quad * 4 + reg;
                if (gi < gj) {
                    unsigned idx = (unsigned)(gi * NN + gj);
                    push1(v1, i1, v2, i2, acc[mi][nj][reg], idx);
                }
            }
        }
    }
    #pragma unroll
    for (int off = 32; off >= 1; off >>= 1) {
        float    w1 = __shfl_down(v1, off);
        unsigned j1 = (unsigned)__shfl_down((int)i1, off);
        float    w2 = __shfl_down(v2, off);
        unsigned j2 = (unsigned)__shfl_down((int)i2, off);
        merge2(v1, i1, v2, i2, w1, j1, w2, j2);
    }
    if (lane == 0) { sv1[wv] = v1; si1[wv] = i1; sv2[wv] = v2; si2[wv] = i2; }
    __syncthreads();
    if (tid == 0) {
        for (int w = 1; w < 4; ++w)
            merge2(v1, i1, v2, i2, sv1[w], si1[w], sv2[w], si2[w]);
        cands[blockIdx.x * 2]     = {v1, i1};
        cands[blockIdx.x * 2 + 1] = {v2, i2};
    }

    // ---- last-block-done: fused finalize ----
    if (tid == 0) {
        __threadfence();                       // release our cands writes
        int c = atomicAdd(&ctrl[0], 1);
        s_last = (c == NBLK - 1) ? 1 : 0;
    }
    __syncthreads();
    if (!s_last) return;
    __threadfence();                           // acquire all blocks' cands

    struct Fin {
        float redv[8]; float s_thresh; int cnt;
        unsigned qidx[256]; double qex[256];
        double wdv1[4], wdv2[4]; unsigned wdi[4];
        double sd1, sd2; unsigned stopi;
        double sacc[256];
    };
    Fin* F = (Fin*)As;                          // reuse dead LDS (~5.3KB < 17.4KB)
    if (tid == 0) F->cnt = 0;

    // Phase A: approx global top-2 values
    float a1 = -INFINITY, a2 = -INFINITY;
    for (int e = tid; e < NC; e += 256) {
        float v = cands[e].v;
        if (v > a1) { a2 = a1; a1 = v; }
        else if (v > a2) a2 = v;
    }
    #pragma unroll
    for (int off = 32; off >= 1; off >>= 1) {
        float w1 = __shfl_down(a1, off);
        float w2 = __shfl_down(a2, off);
        if (w1 > a1) { a2 = (a1 >= w2) ? a1 : w2; a1 = w1; }
        else if (w1 > a2) a2 = w1;
    }
    if (lane == 0) { F->redv[wv * 2] = a1; F->redv[wv * 2 + 1] = a2; }
    __syncthreads();
    if (tid == 0) {
        float b1 = -INFINITY, b2 = -INFINITY;
        for (int e = 0; e < 8; ++e) {
            float v = F->redv[e];
            if (v > b1) { b2 = b1; b1 = v; }
            else if (v > b2) b2 = v;
        }
        F->s_thresh = b2 - 10.0f;   // margin >> fp8 dot-product error bound
    }
    __syncthreads();
    const float thresh = F->s_thresh;

    // Phase B: gather candidates within margin
    for (int e = tid; e < NC; e += 256) {
        if (cands[e].v >= thresh) {
            int k = atomicAdd(&F->cnt, 1);
            if (k < 256) F->qidx[k] = cands[e].idx;
        }
    }
    __syncthreads();
    const int n = F->cnt < 256 ? F->cnt : 256;

    // Phase C: exact double dot per candidate (one wave each)
    for (int c = wv; c < n; c += 4) {
        unsigned idx = F->qidx[c];
        unsigned gi = idx >> 13;
        unsigned gj = idx & 8191;
        const float* pa = x + (size_t)gi * DD;
        const float* pb = x + (size_t)gj * DD;
        double s = (double)pa[lane] * (double)pb[lane]
                 + (double)pa[lane + 64] * (double)pb[lane + 64];
        #pragma unroll
        for (int off = 32; off >= 1; off >>= 1) s += __shfl_down(s, off);
        if (lane == 0) F->qex[c] = s;
    }
    __syncthreads();

    // Phase D: exact top-2, parallel across 256 threads
    double d1 = -DBL_MAX, d2 = -DBL_MAX;
    unsigned bi = 0;
    if (tid < n) { d1 = F->qex[tid]; bi = F->qidx[tid]; }
    #pragma unroll
    for (int off = 32; off >= 1; off >>= 1) {
        double w1   = __shfl_down(d1, off);
        unsigned j1 = (unsigned)__shfl_down((int)bi, off);
        double w2   = __shfl_down(d2, off);
        dmerge2(d1, bi, d2, w1, j1, w2);
    }
    if (lane == 0) { F->wdv1[wv] = d1; F->wdv2[wv] = d2; F->wdi[wv] = bi; }
    __syncthreads();
    if (tid == 0) {
        for (int w = 1; w < 4; ++w)
            dmerge2(d1, bi, d2, F->wdv1[w], F->wdi[w], F->wdv2[w]);
        F->sd1 = d1; F->sd2 = d2; F->stopi = bi;
    }
    __syncthreads();
    const double top1 = F->sd1, top2 = F->sd2;
    const unsigned topi = F->stopi;

    // Phase E: mean(sim_oth / sim_self)
    double accE = 0.0;
    for (int p = tid; p < PP; p += 256) {
        unsigned selfidx = (unsigned)(p * NN + p + 1);
        double so = (topi == selfidx) ? top2 : top1;
        accE += so / ss[p];
    }
    F->sacc[tid] = accE;
    __syncthreads();
    for (int s = 128; s >= 1; s >>= 1) {
        if (tid < s) F->sacc[tid] += F->sacc[tid + s];
        __syncthreads();
    }
    if (tid == 0) out[0] = (float)(F->sacc[0] / (double)PP);
}

extern "C" void kernel_launch(void* const* d_in, const int* in_sizes, int n_in,
                              void* d_out, int out_size, void* d_ws, size_t ws_size,
                              hipStream_t stream) {
    (void)in_sizes; (void)n_in; (void)out_size; (void)ws_size;
    const float* x = (const float*)d_in[0];
    float* out = (float*)d_out;

    double* ss   = (double*)d_ws;                                 // 32 KB
    Cand* cands  = (Cand*)((char*)d_ws + 32768);                  // 33 KB
    int* ctrl    = (int*)((char*)d_ws + 81920);                   // done counter
    unsigned char* xb = (unsigned char*)((char*)d_ws + 131072);   // 1 MB fp8

    k_prep<<<128, 256, 0, stream>>>(x, xb, ss, ctrl);
    k_fused<<<NBLK, 256, 0, stream>>>(xb, x, ss, cands, ctrl, out);
}

// Round 8
// 204.868 us; speedup vs baseline: 1.2923x; 1.2923x over previous
//
#include <hip/hip_runtime.h>
#include <hip/hip_bf16.h>
#include <math.h>
#include <float.h>

// Problem constants (x: [8192,128] f32, n_images=2)
static constexpr int NN    = 8192;
static constexpr int DD    = 128;
static constexpr int PP    = 4096;              // persons
static constexpr int TILE  = 128;
static constexpr int TT    = NN / TILE;         // 64 tiles per dim
static constexpr int NBLK  = TT * (TT + 1) / 2; // 2080 upper-tri tile pairs
static constexpr int NC    = NBLK * 2;          // 2 candidates per tile
static constexpr int GRP   = 1088;              // 8 rows x 128B (fp8) + 64B pad
static constexpr int PLDS  = 16 * GRP;          // 17408 B per 128x128 fp8 panel

using f32x4 = __attribute__((ext_vector_type(4))) float;

typedef const __attribute__((address_space(1))) unsigned int* gas_uint;
typedef __attribute__((address_space(3))) unsigned int* las_uint;

// async 16B/lane global->LDS DMA. LDS dest = wave-uniform base + lane*16.
// Global address may vary per lane. [m03/m97/m104]
__device__ __forceinline__ void dma16(const void* g, const void* l) {
    __builtin_amdgcn_global_load_lds(
        (gas_uint)(unsigned long long)g,
        (las_uint)(unsigned)(unsigned long long)l, 16, 0, 0);
}

__device__ __forceinline__ void push1(float& v1, unsigned& i1, float& v2, unsigned& i2,
                                      float w, unsigned j) {
    if (w > v1) { v2 = v1; i2 = i1; v1 = w; i1 = j; }
    else if (w > v2) { v2 = w; i2 = j; }
}

__device__ __forceinline__ void merge2(float& v1, unsigned& i1, float& v2, unsigned& i2,
                                       float w1, unsigned j1, float w2, unsigned j2) {
    if (w1 > v1) {
        float nv2; unsigned ni2;
        if (v1 >= w2) { nv2 = v1; ni2 = i1; } else { nv2 = w2; ni2 = j2; }
        v1 = w1; i1 = j1; v2 = nv2; i2 = ni2;
    } else if (w1 > v2) {
        v2 = w1; i2 = j1;
    }
}

__device__ __forceinline__ void dmerge2(double& v1, unsigned& i1, double& v2,
                                        double w1, unsigned j1, double w2) {
    if (w1 > v1) {
        double nv2 = (v1 >= w2) ? v1 : w2;
        v2 = nv2; v1 = w1; i1 = j1;
    } else if (w1 > v2) {
        v2 = w1;
    }
}

// ---- kernel 0: x -> fp8 e4m3 (1MB) + sim_self (double) + done-ctr reset.
// 128 blocks (launch-ramp diet): each converts 512 grid-strided chunks and
// computes 32 persons' sim_self. ----
__global__ __launch_bounds__(256) void k_prep(const float* __restrict__ x,
                                              unsigned char* __restrict__ xb,
                                              double* __restrict__ ss,
                                              int* __restrict__ ctrl) {
    const int tid = threadIdx.x;
    const int bid = blockIdx.x;
    if (bid == 0 && tid == 0) ctrl[0] = 0;     // done counter (graph-replay reset)

    // convert: 65536 chunks x 16 floats -> 16 fp8; 2 chunks per thread
    for (int chunk = bid * 256 + tid; chunk < 65536; chunk += 128 * 256) {
        const float4* s = (const float4*)(x + (size_t)chunk * 16);
        float4 f0 = s[0], f1 = s[1], f2 = s[2], f3 = s[3];
        unsigned w0 = 0, w1 = 0, w2 = 0, w3 = 0;
        w0 = __builtin_amdgcn_cvt_pk_fp8_f32(f0.x, f0.y, w0, false);
        w0 = __builtin_amdgcn_cvt_pk_fp8_f32(f0.z, f0.w, w0, true);
        w1 = __builtin_amdgcn_cvt_pk_fp8_f32(f1.x, f1.y, w1, false);
        w1 = __builtin_amdgcn_cvt_pk_fp8_f32(f1.z, f1.w, w1, true);
        w2 = __builtin_amdgcn_cvt_pk_fp8_f32(f2.x, f2.y, w2, false);
        w2 = __builtin_amdgcn_cvt_pk_fp8_f32(f2.z, f2.w, w2, true);
        w3 = __builtin_amdgcn_cvt_pk_fp8_f32(f3.x, f3.y, w3, false);
        w3 = __builtin_amdgcn_cvt_pk_fp8_f32(f3.z, f3.w, w3, true);
        uint4 o = {w0, w1, w2, w3};
        *(uint4*)(xb + (size_t)chunk * 16) = o;
    }

    // sim_self[p] = dot(x[p], x[p+1]) in double, wave per person, 8 each
    const int wv = tid >> 6, lane = tid & 63;
    #pragma unroll
    for (int u = 0; u < 8; ++u) {
        int p = bid * 32 + wv * 8 + u;         // 0..4095
        const float* a  = x + (size_t)p * DD;
        const float* bb = a + DD;
        double s = (double)a[lane] * (double)bb[lane]
                 + (double)a[lane + 64] * (double)bb[lane + 64];
        #pragma unroll
        for (int off = 32; off >= 1; off >>= 1) s += __shfl_down(s, off);
        if (lane == 0) ss[p] = s;
    }
}

// ---- kernel 1 (fused): verbatim R3 fp8 MFMA top-2 body + last-block-done
// finalize. Cross-XCD visibility of cands via AGENT-SCOPE atomic stores/loads
// (sc1 write-through, no L2 writeback) -- NO __threadfence (R7's per-block
// buffer_wbl2 storm: WRITE_SIZE 35MB, 2.2x slowdown). ----
__global__ __launch_bounds__(256, 4) void k_fused(const unsigned char* __restrict__ xb,
                                                  const float* __restrict__ x,
                                                  const double* __restrict__ ss,
                                                  unsigned long long* __restrict__ cands,
                                                  int* __restrict__ ctrl,
                                                  float* __restrict__ out) {
    __shared__ __align__(16) char As[PLDS];
    __shared__ __align__(16) char Bs[PLDS];
    __shared__ float sv1[4], sv2[4];
    __shared__ unsigned si1[4], si2[4];
    __shared__ int s_last;

    const int tid  = threadIdx.x;
    const int wv   = tid >> 6;      // wave 0..3
    const int lane = tid & 63;

    // decode linear block id -> (ti, tj), ti <= tj
    int rem = blockIdx.x;
    int ti = 0;
    while (rem >= TT - ti) { rem -= (TT - ti); ++ti; }
    const int tj = ti + rem;

    // ---- stage both 128x128 fp8 panels, single phase, 8 dma16 per wave.
    // group = 8 rows x 128B. Source col XOR-swizzled by (row_in<<4) so the
    // linear LDS write gives conflict-free fragment reads.
    {
        const int grow = lane >> 3;                 // 0..7
        const int colb = ((lane & 7) * 16) ^ (grow << 4);
        #pragma unroll
        for (int t = 0; t < 4; ++t) {
            int g = wv * 4 + t;                     // group 0..15
            dma16(xb + (size_t)(ti * TILE + g * 8 + grow) * DD + colb, As + g * GRP);
            dma16(xb + (size_t)(tj * TILE + g * 8 + grow) * DD + colb, Bs + g * GRP);
        }
    }
    __syncthreads();   // vmcnt(0) drain before s_barrier -> DMA landed

    const int wm   = wv >> 1;       // wave row 0..1 (64 rows)
    const int wn   = wv & 1;        // wave col 0..1 (64 cols)
    const int quad = lane >> 4;     // 0..3
    const int r16  = lane & 15;     // 0..15
    const int rl   = r16 & 7;       // row within group
    const int rh   = r16 >> 3;      // group parity within 16-row fragment
    const int xs   = rl << 4;       // XOR term matching the staging swizzle

    const char* Abase = As + (wm * 8 + rh) * GRP + rl * 128 + (quad & 1) * 8;
    const char* Bbase = Bs + (wn * 8 + rh) * GRP + rl * 128 + (quad & 1) * 8;

    f32x4 acc[4][4];
    #pragma unroll
    for (int mi = 0; mi < 4; ++mi)
        #pragma unroll
        for (int nj = 0; nj < 4; ++nj)
            acc[mi][nj] = (f32x4){0.f, 0.f, 0.f, 0.f};

    #pragma unroll
    for (int kc = 0; kc < 4; ++kc) {        // 4 chunks of K=32
        const int co = (kc * 32 + (quad >> 1) * 16) ^ xs;
        long af[4], bq[4];
        #pragma unroll
        for (int mi = 0; mi < 4; ++mi) {
            af[mi] = *(const long*)(Abase + mi * (2 * GRP) + co);
            bq[mi] = *(const long*)(Bbase + mi * (2 * GRP) + co);
        }
        #pragma unroll
        for (int mi = 0; mi < 4; ++mi)
            #pragma unroll
            for (int nj = 0; nj < 4; ++nj)
                acc[mi][nj] = __builtin_amdgcn_mfma_f32_16x16x32_fp8_fp8(
                    af[mi], bq[nj], acc[mi][nj], 0, 0, 0);
    }

    // ---- epilogue: per-lane top-2 over valid (i<j) ----
    // C/D layout: col = lane&15, row = (lane>>4)*4 + reg (dtype-independent)
    const int ibase = ti * TILE + wm * 64;
    const int jbase = tj * TILE + wn * 64;
    float v1 = -INFINITY, v2 = -INFINITY;
    unsigned i1 = 0, i2 = 0;
    #pragma unroll
    for (int mi = 0; mi < 4; ++mi) {
        #pragma unroll
        for (int nj = 0; nj < 4; ++nj) {
            int gj = jbase + nj * 16 + r16;
            #pragma unroll
            for (int reg = 0; reg < 4; ++reg) {
                int gi = ibase + mi * 16 + quad * 4 + reg;
                if (gi < gj) {
                    unsigned idx = (unsigned)(gi * NN + gj);
                    push1(v1, i1, v2, i2, acc[mi][nj][reg], idx);
                }
            }
        }
    }
    #pragma unroll
    for (int off = 32; off >= 1; off >>= 1) {
        float    w1 = __shfl_down(v1, off);
        unsigned j1 = (unsigned)__shfl_down((int)i1, off);
        float    w2 = __shfl_down(v2, off);
        unsigned j2 = (unsigned)__shfl_down((int)i2, off);
        merge2(v1, i1, v2, i2, w1, j1, w2, j2);
    }
    if (lane == 0) { sv1[wv] = v1; si1[wv] = i1; sv2[wv] = v2; si2[wv] = i2; }
    __syncthreads();
    if (tid == 0) {
        for (int w = 1; w < 4; ++w)
            merge2(v1, i1, v2, i2, sv1[w], si1[w], sv2[w], si2[w]);
        // agent-scope (device-coherent) stores: visible across XCDs without
        // any L2 writeback. pack = idx<<32 | f32 bits.
        unsigned long long e1 = ((unsigned long long)i1 << 32) | __float_as_uint(v1);
        unsigned long long e2 = ((unsigned long long)i2 << 32) | __float_as_uint(v2);
        __hip_atomic_store(&cands[blockIdx.x * 2],     e1,
                           __ATOMIC_RELAXED, __HIP_MEMORY_SCOPE_AGENT);
        __hip_atomic_store(&cands[blockIdx.x * 2 + 1], e2,
                           __ATOMIC_RELAXED, __HIP_MEMORY_SCOPE_AGENT);
        asm volatile("s_waitcnt vmcnt(0)" ::: "memory");  // stores at coherent point
        int c = __hip_atomic_fetch_add(&ctrl[0], 1,
                                       __ATOMIC_RELAXED, __HIP_MEMORY_SCOPE_AGENT);
        s_last = (c == NBLK - 1) ? 1 : 0;
    }
    __syncthreads();
    if (!s_last) return;

    // ---- last-block finalize (one block on the whole chip) ----
    struct Fin {
        float redv[8]; float s_thresh; int cnt;
        unsigned qidx[256]; double qex[256];
        double wdv1[4], wdv2[4]; unsigned wdi[4];
        double sd1, sd2; unsigned stopi;
        double sacc[256];
    };
    Fin* F = (Fin*)As;                          // reuse dead LDS (~5.3KB < 17.4KB)
    if (tid == 0) F->cnt = 0;

    // Phase A: approx global top-2 values (agent-scope loads: always coherent)
    float a1 = -INFINITY, a2 = -INFINITY;
    for (int e = tid; e < NC; e += 256) {
        unsigned long long u = __hip_atomic_load(&cands[e], __ATOMIC_RELAXED,
                                                 __HIP_MEMORY_SCOPE_AGENT);
        float v = __uint_as_float((unsigned)u);
        if (v > a1) { a2 = a1; a1 = v; }
        else if (v > a2) a2 = v;
    }
    #pragma unroll
    for (int off = 32; off >= 1; off >>= 1) {
        float w1 = __shfl_down(a1, off);
        float w2 = __shfl_down(a2, off);
        if (w1 > a1) { a2 = (a1 >= w2) ? a1 : w2; a1 = w1; }
        else if (w1 > a2) a2 = w1;
    }
    if (lane == 0) { F->redv[wv * 2] = a1; F->redv[wv * 2 + 1] = a2; }
    __syncthreads();
    if (tid == 0) {
        float b1 = -INFINITY, b2 = -INFINITY;
        for (int e = 0; e < 8; ++e) {
            float v = F->redv[e];
            if (v > b1) { b2 = b1; b1 = v; }
            else if (v > b2) b2 = v;
        }
        F->s_thresh = b2 - 10.0f;   // margin >> fp8 dot-product error bound
    }
    __syncthreads();
    const float thresh = F->s_thresh;

    // Phase B: gather candidates within margin
    for (int e = tid; e < NC; e += 256) {
        unsigned long long u = __hip_atomic_load(&cands[e], __ATOMIC_RELAXED,
                                                 __HIP_MEMORY_SCOPE_AGENT);
        float v = __uint_as_float((unsigned)u);
        if (v >= thresh) {
            int k = atomicAdd(&F->cnt, 1);
            if (k < 256) F->qidx[k] = (unsigned)(u >> 32);
        }
    }
    __syncthreads();
    const int n = F->cnt < 256 ? F->cnt : 256;

    // Phase C: exact double dot per candidate (one wave each)
    for (int c = wv; c < n; c += 4) {
        unsigned idx = F->qidx[c];
        unsigned gi = idx >> 13;
        unsigned gj = idx & 8191;
        const float* pa = x + (size_t)gi * DD;
        const float* pb = x + (size_t)gj * DD;
        double s = (double)pa[lane] * (double)pb[lane]
                 + (double)pa[lane + 64] * (double)pb[lane + 64];
        #pragma unroll
        for (int off = 32; off >= 1; off >>= 1) s += __shfl_down(s, off);
        if (lane == 0) F->qex[c] = s;
    }
    __syncthreads();

    // Phase D: exact top-2, parallel across 256 threads
    double d1 = -DBL_MAX, d2 = -DBL_MAX;
    unsigned bi = 0;
    if (tid < n) { d1 = F->qex[tid]; bi = F->qidx[tid]; }
    #pragma unroll
    for (int off = 32; off >= 1; off >>= 1) {
        double w1   = __shfl_down(d1, off);
        unsigned j1 = (unsigned)__shfl_down((int)bi, off);
        double w2   = __shfl_down(d2, off);
        dmerge2(d1, bi, d2, w1, j1, w2);
    }
    if (lane == 0) { F->wdv1[wv] = d1; F->wdv2[wv] = d2; F->wdi[wv] = bi; }
    __syncthreads();
    if (tid == 0) {
        for (int w = 1; w < 4; ++w)
            dmerge2(d1, bi, d2, F->wdv1[w], F->wdi[w], F->wdv2[w]);
        F->sd1 = d1; F->sd2 = d2; F->stopi = bi;
    }
    __syncthreads();
    const double top1 = F->sd1, top2 = F->sd2;
    const unsigned topi = F->stopi;

    // Phase E: mean(sim_oth / sim_self)
    double accE = 0.0;
    for (int p = tid; p < PP; p += 256) {
        unsigned selfidx = (unsigned)(p * NN + p + 1);
        double so = (topi == selfidx) ? top2 : top1;
        accE += so / ss[p];
    }
    F->sacc[tid] = accE;
    __syncthreads();
    for (int s = 128; s >= 1; s >>= 1) {
        if (tid < s) F->sacc[tid] += F->sacc[tid + s];
        __syncthreads();
    }
    if (tid == 0) out[0] = (float)(F->sacc[0] / (double)PP);
}

extern "C" void kernel_launch(void* const* d_in, const int* in_sizes, int n_in,
                              void* d_out, int out_size, void* d_ws, size_t ws_size,
                              hipStream_t stream) {
    (void)in_sizes; (void)n_in; (void)out_size; (void)ws_size;
    const float* x = (const float*)d_in[0];
    float* out = (float*)d_out;

    double* ss   = (double*)d_ws;                                       // 32 KB
    unsigned long long* cands = (unsigned long long*)((char*)d_ws + 32768); // 33 KB
    int* ctrl    = (int*)((char*)d_ws + 81920);                         // done counter
    unsigned char* xb = (unsigned char*)((char*)d_ws + 131072);         // 1 MB fp8

    k_prep<<<128, 256, 0, stream>>>(x, xb, ss, ctrl);
    k_fused<<<NBLK, 256, 0, stream>>>(xb, x, ss, cands, ctrl, out);
}